// Round 3
// baseline (139.094 us; speedup 1.0000x reference)
//
#include <hip/hip_runtime.h>
#include <math.h>

#define NB 2
#define NH 8
#define SS 160
#define DD 64
#define MFIX 40.0f

// k1 LDS map (81920 B total -> exactly 2 blocks/CU):
//   main loop : WB0 [0,20480)  WB1 [20480,40960)  A1L [75360,81920)
//   epilogue  : V2T [0,13312)  A2 [13312,46592)   A1L persists
#define WB_SZ   20480
#define WB_HALF 10240
#define PV_ROWB 208              // 104 bf16 slots/row; K padded 80->96, rest unread
#define V2T_OFF 0
#define A2_OFF  13312
#define A1L_OFF 75360
#define A1L_STR 164

typedef __attribute__((ext_vector_type(8))) short bf16x8;
typedef __attribute__((ext_vector_type(4))) float f32x4;

#define MFMA16(a, b, c) __builtin_amdgcn_mfma_f32_16x16x32_bf16(a, b, c, 0, 0, 0)

// split a pair of fp32 into packed bf16 (hi, lo); lo captures the residual.
__device__ __forceinline__ uint2 splitpair(float a0, float a1) {
    unsigned u0 = __float_as_uint(a0), u1 = __float_as_uint(a1);
    unsigned hi = (u0 >> 16) | (u1 & 0xffff0000u);
    float r0 = a0 - __uint_as_float(u0 & 0xffff0000u);
    float r1 = a1 - __uint_as_float(u1 & 0xffff0000u);
    unsigned v0 = __float_as_uint(r0), v1 = __float_as_uint(r1);
    unsigned lo = (v0 >> 16) | (v1 & 0xffff0000u);
    return make_uint2(hi, lo);
}

// Block = (bh, s-chunk of 10, t-half of 80). 512 blocks, 10 waves each; wave
// owns 16 q rows x 80 t. scores[q,(s,t)] = Q.W^T with W[(s,t),d]=k1[s,d]k2[t,d]
// staged per-s as bf16 hi/lo (3-term MFMA). Fixed shift MFIX; all outputs are
// additive partials over (s-chunk, t-half) -> zp/lp workspace, k2 reduces.
__global__ __launch_bounds__(640, 5) void tritt_k1(
    const float* __restrict__ q,  const float* __restrict__ k1,
    const float* __restrict__ k2, const float* __restrict__ v1,
    const float* __restrict__ v2, float* __restrict__ zp, float* __restrict__ lp)
{
    __shared__ __align__(16) char sm[81920];

    const int tid  = threadIdx.x;
    const int bh   = blockIdx.x >> 5;
    const int cidx = blockIdx.x & 31;       // 32 partials per bh
    const int sck  = cidx >> 1;             // s in [10*sck, +10)
    const int th   = cidx & 1;              // t in [80*th, +80)
    const size_t base = (size_t)bh * SS * DD;
    const int t0 = 80 * th, sbase = 10 * sck;

    const int lane = tid & 63, wid = tid >> 6;
    const int n16  = lane & 15, quad = lane >> 4;

    // ---- Q fragments (persistent): row 16*wid+n16, k = kc*32+quad*8+e ----
    bf16x8 qh[2], ql[2];
    #pragma unroll
    for (int kc = 0; kc < 2; ++kc) {
        const float4* qp = (const float4*)(q + base
            + (size_t)(16*wid + n16) * DD + kc*32 + quad*8);
        float4 a = qp[0], b = qp[1];
        uint2 p0 = splitpair(a.x, a.y), p1 = splitpair(a.z, a.w);
        uint2 p2 = splitpair(b.x, b.y), p3 = splitpair(b.z, b.w);
        uint4 hh = make_uint4(p0.x, p1.x, p2.x, p3.x);
        uint4 ll = make_uint4(p0.y, p1.y, p2.y, p3.y);
        qh[kc] = *(bf16x8*)&hh;
        ql[kc] = *(bf16x8*)&ll;
    }

    // ---- staging: one (t, 8-d group) per thread ----
    const int st = tid >> 3, sg = tid & 7;
    auto stageW = [&](int sl) {             // tile s = sbase+sl -> buf sl&1
        char* dst = sm + (sl & 1) * WB_SZ;
        const float4* yp = (const float4*)(k2 + base + (size_t)(t0 + st) * DD + sg*8);
        const float4* xp = (const float4*)(k1 + base + (size_t)(sbase + sl) * DD + sg*8);
        float4 y0 = yp[0], y1 = yp[1], x0 = xp[0], x1 = xp[1];
        uint2 p0 = splitpair(x0.x*y0.x, x0.y*y0.y);
        uint2 p1 = splitpair(x0.z*y0.z, x0.w*y0.w);
        uint2 p2 = splitpair(x1.x*y1.x, x1.y*y1.y);
        uint2 p3 = splitpair(x1.z*y1.z, x1.w*y1.w);
        char* d = dst + st*128 + ((sg ^ (st & 7)) * 16);
        *(uint4*)d             = make_uint4(p0.x, p1.x, p2.x, p3.x);
        *(uint4*)(d + WB_HALF) = make_uint4(p0.y, p1.y, p2.y, p3.y);
    };
    auto stageV2T = [&]() {                 // v2 half -> [64 d][PV rows] bf16
        const float4* vp = (const float4*)(v2 + base + (size_t)(t0 + st) * DD + sg*8);
        float4 a = vp[0], b = vp[1];
        float vals[8] = {a.x,a.y,a.z,a.w, b.x,b.y,b.z,b.w};
        #pragma unroll
        for (int i = 0; i < 8; ++i) {
            unsigned u = (__float_as_uint(vals[i]) + 0x8000u) >> 16;
            *(unsigned short*)(sm + V2T_OFF + (size_t)(sg*8 + i)*PV_ROWB + st*2)
                = (unsigned short)u;
        }
    };

    float* A1L = (float*)(sm + A1L_OFF);    // [10 s][164] partial row sums

    stageW(0);
    __syncthreads();

    f32x4 a2run[5];
    #pragma unroll
    for (int jj = 0; jj < 5; ++jj) a2run[jj] = (f32x4){0.f,0.f,0.f,0.f};

    const int slot0 = (quad ^ (n16 & 7)) * 16;
    const int slot1 = ((4 + quad) ^ (n16 & 7)) * 16;

    // ---- main loop: 10 s-tiles, double-buffered W, 1 barrier/tile ----
    #pragma unroll 1
    for (int sl = 0; sl < 10; ++sl) {
        if (sl < 9) stageW(sl + 1); else stageV2T();

        const char* wb = sm + (sl & 1) * WB_SZ;
        f32x4 acc[5];
        #pragma unroll
        for (int jj = 0; jj < 5; ++jj) acc[jj] = (f32x4){0.f,0.f,0.f,0.f};

        #pragma unroll
        for (int jj = 0; jj < 5; ++jj) {
            const char* rb = wb + (16*jj + n16) * 128;
            bf16x8 wh0 = *(const bf16x8*)(rb + slot0);
            bf16x8 wl0 = *(const bf16x8*)(rb + slot0 + WB_HALF);
            bf16x8 wh1 = *(const bf16x8*)(rb + slot1);
            bf16x8 wl1 = *(const bf16x8*)(rb + slot1 + WB_HALF);
            acc[jj] = MFMA16(qh[0], wh0, acc[jj]);
            acc[jj] = MFMA16(ql[0], wh0, acc[jj]);
            acc[jj] = MFMA16(qh[0], wl0, acc[jj]);
            acc[jj] = MFMA16(qh[1], wh1, acc[jj]);
            acc[jj] = MFMA16(ql[1], wh1, acc[jj]);
            acc[jj] = MFMA16(qh[1], wl1, acc[jj]);
        }

        // exp with fixed shift; accumulate A2 (regs) + row-sum partials
        float prs[4] = {0.f, 0.f, 0.f, 0.f};
        #pragma unroll
        for (int jj = 0; jj < 5; ++jj)
            #pragma unroll
            for (int r = 0; r < 4; ++r) {
                float e = __expf(acc[jj][r] - MFIX);
                a2run[jj][r] += e;
                prs[r] += e;
            }
        // full row (80 t) lives in this wave: reduce over n16, direct store
        #pragma unroll
        for (int r = 0; r < 4; ++r) {
            float v = prs[r];
            v += __shfl_xor(v, 1, 64); v += __shfl_xor(v, 2, 64);
            v += __shfl_xor(v, 4, 64); v += __shfl_xor(v, 8, 64);
            if (n16 == 0) A1L[sl*A1L_STR + 16*wid + 4*quad + r] = v;
        }
        __syncthreads();
    }

    // ---- epilogue phase 1: A2 -> LDS bf16, zero K-pads, lp ----
    #pragma unroll
    for (int jj = 0; jj < 5; ++jj)
        #pragma unroll
        for (int r = 0; r < 4; ++r) {
            unsigned u = (__float_as_uint(a2run[jj][r]) + 0x8000u) >> 16;
            *(unsigned short*)(sm + A2_OFF + (16*wid + 4*quad + r)*PV_ROWB
                               + (16*jj + n16)*2) = (unsigned short)u;
        }
    #pragma unroll
    for (int i = tid; i < 160*8; i += 640) {          // A2 cols 80..95 = 0
        int qq = i >> 3, w = i & 7;
        *(unsigned*)(sm + A2_OFF + qq*PV_ROWB + 160 + w*4) = 0u;
    }
    if (tid < 64*8) {                                  // V2T cols 80..95 = 0
        int dd2 = tid >> 3, w = tid & 7;
        *(unsigned*)(sm + V2T_OFF + dd2*PV_ROWB + 160 + w*4) = 0u;
    }
    if (tid < SS) {
        float l = 0.f;
        #pragma unroll
        for (int s2 = 0; s2 < 10; ++s2) l += A1L[s2*A1L_STR + tid];
        lp[(size_t)(bh*32 + cidx)*SS + tid] = l;
    }
    __syncthreads();

    // ---- PV: zacc[q,d] = A2 @ v2 (MFMA, K=96 padded) + A1 @ v1 (VALU) ----
    f32x4 zacc[4];
    #pragma unroll
    for (int jd = 0; jd < 4; ++jd) zacc[jd] = (f32x4){0.f,0.f,0.f,0.f};

    const char* ap = sm + A2_OFF + (16*wid + n16)*PV_ROWB;
    #pragma unroll
    for (int kc = 0; kc < 3; ++kc) {
        bf16x8 af = *(const bf16x8*)(ap + (kc*32 + quad*8)*2);
        #pragma unroll
        for (int jd = 0; jd < 4; ++jd) {
            bf16x8 bfr = *(const bf16x8*)(sm + V2T_OFF + (16*jd + n16)*PV_ROWB
                                          + (kc*32 + quad*8)*2);
            zacc[jd] = MFMA16(af, bfr, zacc[jd]);
        }
    }
    const float* v1p = v1 + base + (size_t)sbase * DD;
    #pragma unroll 1
    for (int s2 = 0; s2 < 10; ++s2) {
        float a10 = A1L[s2*A1L_STR + 16*wid + 4*quad + 0];
        float a11 = A1L[s2*A1L_STR + 16*wid + 4*quad + 1];
        float a12 = A1L[s2*A1L_STR + 16*wid + 4*quad + 2];
        float a13 = A1L[s2*A1L_STR + 16*wid + 4*quad + 3];
        #pragma unroll
        for (int jd = 0; jd < 4; ++jd) {
            float vv = v1p[s2*DD + 16*jd + n16];
            zacc[jd][0] = fmaf(a10, vv, zacc[jd][0]);
            zacc[jd][1] = fmaf(a11, vv, zacc[jd][1]);
            zacc[jd][2] = fmaf(a12, vv, zacc[jd][2]);
            zacc[jd][3] = fmaf(a13, vv, zacc[jd][3]);
        }
    }
    float* zpb = zp + (size_t)(bh*32 + cidx) * SS * DD;
    #pragma unroll
    for (int jd = 0; jd < 4; ++jd)
        #pragma unroll
        for (int r = 0; r < 4; ++r)
            zpb[(16*wid + 4*quad + r)*DD + 16*jd + n16] = zacc[jd][r];
}

__global__ __launch_bounds__(256) void tritt_k2(
    const float* __restrict__ zp, const float* __restrict__ lp,
    float* __restrict__ out)
{
    int b  = blockIdx.x;                 // 640 blocks: (bh, 4-q group)
    int bh = b / 40;
    int qq = (b % 40)*4 + (threadIdx.x >> 6);
    int d  = threadIdx.x & 63;
    float zs = 0.f, ls = 0.f;
    #pragma unroll 1
    for (int c = 0; c < 32; ++c) {
        zs += zp[((size_t)(bh*32 + c)*SS + qq)*DD + d];
        ls += lp[(size_t)(bh*32 + c)*SS + qq];
    }
    out[((size_t)bh*SS + qq)*DD + d] = zs / ls;
    if (d == 0)
        out[(size_t)NB*NH*SS*DD + (size_t)bh*SS + qq] = MFIX + __logf(ls);
}

// ====================== fallback (round-1 kernel, verified) ======================
#define FNT 640
#define FNW 10
__global__ __launch_bounds__(FNT, 5) void tritt_fallback(
    const float* __restrict__ q,  const float* __restrict__ k1,
    const float* __restrict__ k2, const float* __restrict__ v1,
    const float* __restrict__ v2, float* __restrict__ out)
{
    __shared__ __align__(16) char sm[40960];
    const int tid = threadIdx.x;
    const int blk = blockIdx.x;
    const int bh  = blk / SS;
    const int qi  = blk % SS;
    const size_t base = (size_t)bh * SS * DD;
    const float4* k1f = (const float4*)(k1 + base);
    const float4* k2f = (const float4*)(k2 + base);
    const float4* qf  = (const float4*)(q + base + (size_t)qi * DD);
    const int lane = tid & 63;
    const int wid  = tid >> 6;
    const int n16  = lane & 15, quad = lane >> 4;
    const int s0   = 16 * wid;
    const int ssg  = tid >> 2;
    const int sgg  = tid & 3;
    const int soff = ssg * 64 + ((sgg ^ (ssg & 3)) * 16);
    const char* abase = sm + (s0 + n16) * 64 + ((quad ^ (n16 & 3)) * 16);
    const char* bbase = sm + 20480 + n16 * 64 + ((quad ^ (n16 & 3)) * 16);
    f32x4 acc[FNW];
    #pragma unroll
    for (int j = 0; j < FNW; ++j) acc[j] = (f32x4){0.f, 0.f, 0.f, 0.f};
    #pragma unroll
    for (int ks = 0; ks < 2; ++ks) {
        int fg = ssg * 16 + ks * 8 + sgg * 2;
        float4 x0 = k1f[fg], x1 = k1f[fg + 1];
        float4 y0 = k2f[fg], y1 = k2f[fg + 1];
        float4 q0 = qf[ks * 8 + sgg * 2], q1 = qf[ks * 8 + sgg * 2 + 1];
        uint2 pa0 = splitpair(x0.x * q0.x, x0.y * q0.y);
        uint2 pa1 = splitpair(x0.z * q0.z, x0.w * q0.w);
        uint2 pa2 = splitpair(x1.x * q1.x, x1.y * q1.y);
        uint2 pa3 = splitpair(x1.z * q1.z, x1.w * q1.w);
        uint2 pb0 = splitpair(y0.x, y0.y);
        uint2 pb1 = splitpair(y0.z, y0.w);
        uint2 pb2 = splitpair(y1.x, y1.y);
        uint2 pb3 = splitpair(y1.z, y1.w);
        *(uint4*)(sm + soff)         = make_uint4(pa0.x, pa1.x, pa2.x, pa3.x);
        *(uint4*)(sm + 10240 + soff) = make_uint4(pa0.y, pa1.y, pa2.y, pa3.y);
        *(uint4*)(sm + 20480 + soff) = make_uint4(pb0.x, pb1.x, pb2.x, pb3.x);
        *(uint4*)(sm + 30720 + soff) = make_uint4(pb0.y, pb1.y, pb2.y, pb3.y);
        __syncthreads();
        bf16x8 ah = *(const bf16x8*)(abase);
        bf16x8 al = *(const bf16x8*)(abase + 10240);
        #pragma unroll
        for (int j = 0; j < FNW; ++j) {
            bf16x8 bh8 = *(const bf16x8*)(bbase + 1024 * j);
            bf16x8 bl8 = *(const bf16x8*)(bbase + 10240 + 1024 * j);
            acc[j] = MFMA16(ah, bh8, acc[j]);
            acc[j] = MFMA16(al, bh8, acc[j]);
            acc[j] = MFMA16(ah, bl8, acc[j]);
        }
        __syncthreads();
    }
    float* A1   = (float*)sm;
    float* wred = A1 + SS;
    float* colp = wred + 20;
    float* A2   = colp + FNW * SS;
    float* zred = A2 + SS;
    float mloc = -1e30f;
    #pragma unroll
    for (int j = 0; j < FNW; ++j)
        #pragma unroll
        for (int r = 0; r < 4; ++r) mloc = fmaxf(mloc, acc[j][r]);
    #pragma unroll
    for (int off = 32; off; off >>= 1) mloc = fmaxf(mloc, __shfl_xor(mloc, off, 64));
    if (lane == 0) wred[wid] = mloc;
    __syncthreads();
    float m = wred[0];
    #pragma unroll
    for (int w = 1; w < FNW; ++w) m = fmaxf(m, wred[w]);
    float lsum = 0.f;
    #pragma unroll
    for (int j = 0; j < FNW; ++j)
        #pragma unroll
        for (int r = 0; r < 4; ++r) {
            float e = __expf(acc[j][r] - m);
            acc[j][r] = e;
            lsum += e;
        }
    #pragma unroll
    for (int off = 32; off; off >>= 1) lsum += __shfl_xor(lsum, off, 64);
    if (lane == 0) wred[FNW + wid] = lsum;
    #pragma unroll
    for (int r = 0; r < 4; ++r) {
        float rs = 0.f;
        #pragma unroll
        for (int j = 0; j < FNW; ++j) rs += acc[j][r];
        rs += __shfl_xor(rs, 1, 64); rs += __shfl_xor(rs, 2, 64);
        rs += __shfl_xor(rs, 4, 64); rs += __shfl_xor(rs, 8, 64);
        if (n16 == 0) A1[s0 + 4 * quad + r] = rs;
    }
    #pragma unroll
    for (int j = 0; j < FNW; ++j) {
        float cs = (acc[j][0] + acc[j][1]) + (acc[j][2] + acc[j][3]);
        cs += __shfl_xor(cs, 16, 64);
        cs += __shfl_xor(cs, 32, 64);
        if (quad == 0) colp[wid * SS + 16 * j + n16] = cs;
    }
    __syncthreads();
    float l = 0.f;
    #pragma unroll
    for (int w = 0; w < FNW; ++w) l += wred[FNW + w];
    if (tid < SS) {
        float s2 = 0.f;
        #pragma unroll
        for (int w = 0; w < FNW; ++w) s2 += colp[w * SS + tid];
        A2[tid] = s2;
    }
    if (tid == 0)
        out[(size_t)NB * NH * SS * DD + (size_t)bh * SS + qi] = m + __logf(l);
    __syncthreads();
    const int d    = tid & 63;
    const int part = tid >> 6;
    const float* v1p = v1 + base;
    const float* v2p = v2 + base;
    float z = 0.f;
    #pragma unroll 4
    for (int s = part * 16; s < part * 16 + 16; ++s)
        z = fmaf(A1[s], v1p[s * DD + d], fmaf(A2[s], v2p[s * DD + d], z));
    zred[tid] = z;
    __syncthreads();
    if (tid < DD) {
        float zz = 0.f;
        #pragma unroll
        for (int kk = 0; kk < FNW; ++kk) zz += zred[tid + DD * kk];
        out[((size_t)bh * SS + qi) * DD + tid] = zz / l;
    }
}

extern "C" void kernel_launch(void* const* d_in, const int* in_sizes, int n_in,
                              void* d_out, int out_size, void* d_ws, size_t ws_size,
                              hipStream_t stream) {
    const float* q  = (const float*)d_in[0];
    const float* k1 = (const float*)d_in[1];
    const float* k2 = (const float*)d_in[2];
    const float* v1 = (const float*)d_in[3];
    const float* v2 = (const float*)d_in[4];
    float* out = (float*)d_out;
    const size_t zp_elems = (size_t)16 * 32 * SS * DD;   // [bh][partial][q][d]
    const size_t lp_elems = (size_t)16 * 32 * SS;        // [bh][partial][q]
    const size_t need = (zp_elems + lp_elems) * sizeof(float);
    if (ws_size >= need && d_ws != nullptr) {
        float* zp = (float*)d_ws;
        float* lp = zp + zp_elems;
        tritt_k1<<<dim3(512), dim3(640), 0, stream>>>(q, k1, k2, v1, v2, zp, lp);
        tritt_k2<<<dim3(640), dim3(256), 0, stream>>>(zp, lp, out);
    } else {
        tritt_fallback<<<dim3(NB * NH * SS), dim3(FNT), 0, stream>>>(q, k1, k2, v1, v2, out);
    }
}